// Round 1
// baseline (2663.291 us; speedup 1.0000x reference)
//
#include <hip/hip_runtime.h>
#include <hip/hip_bf16.h>

#define NNODES 100000
#define NEDGES 1600000
#define ETOT   (NEDGES + NNODES)

struct WSrc { const void* p[12]; };

__device__ __forceinline__ float ld_f(const void* p, long i, int f32) {
  if (f32) return ((const float*)p)[i];
  return __bfloat162float(((const __hip_bfloat16*)p)[i]);
}

// ---------------- dtype detection ----------------
// flags[0]: 1 => edge_index is int64 (odd int32 words all zero), else int32
// flags[1]: 1 => float buffers are fp32 (low-half ushorts have random exponents), else bf16
__global__ void detect_kernel(const void* xraw, const void* eraw, int* flags) {
  __shared__ int cnt0, cnt1;
  if (threadIdx.x == 0) { cnt0 = 0; cnt1 = 0; }
  __syncthreads();
  const int* e32 = (const int*)eraw;
  int nz = 0;
  for (int i = threadIdx.x; i < 2048; i += blockDim.x) nz += (e32[2 * i + 1] != 0);
  const unsigned short* xs = (const unsigned short*)xraw;
  int weird = 0;
  for (int i = threadIdx.x; i < 4096; i += blockDim.x) {
    unsigned short u = xs[2 * i];
    int ex = (u >> 7) & 0xFF;
    weird += (ex > 168 || (ex < 88 && ex != 0)) ? 1 : 0;
  }
  atomicAdd(&cnt0, nz);
  atomicAdd(&cnt1, weird);
  __syncthreads();
  if (threadIdx.x == 0) {
    flags[0] = (cnt0 < 1024) ? 1 : 0;
    flags[1] = (cnt1 > 512) ? 1 : 0;
  }
}

// ---------------- input normalization to fp32 / int32 ----------------
__global__ void conv_f32_kernel(const void* src, float* dst, long n, const int* flags) {
  int f32 = flags[1];
  long stride = (long)gridDim.x * blockDim.x;
  for (long i = (long)blockIdx.x * blockDim.x + threadIdx.x; i < n; i += stride)
    dst[i] = ld_f(src, i, f32);
}

__global__ void conv_wts_kernel(WSrc wsrc, float* dst, const int* flags) {
  const int start[13] = {0, 16384, 16512, 16640, 16768, 33152, 33280, 33408,
                         33536, 49920, 50048, 50176, 50304};
  int f32 = flags[1];
  int stride = gridDim.x * blockDim.x;
  for (int i = blockIdx.x * blockDim.x + threadIdx.x; i < 50304; i += stride) {
    int s = 0;
    while (start[s + 1] <= i) s++;
    dst[i] = ld_f(wsrc.p[s], i - start[s], f32);
  }
}

__global__ void conv_edges_kernel(const void* raw, int* src32, int* dst32, const int* flags) {
  int i64 = flags[0];
  long stride = (long)gridDim.x * blockDim.x;
  for (long e = (long)blockIdx.x * blockDim.x + threadIdx.x; e < NEDGES; e += stride) {
    if (i64) {
      const long long* r = (const long long*)raw;
      src32[e] = (int)r[e];
      dst32[e] = (int)r[NEDGES + e];
    } else {
      const int* r = (const int*)raw;
      src32[e] = r[e];
      dst32[e] = r[NEDGES + e];
    }
  }
}

// ---------------- CSR build (by dst, self-loops appended) ----------------
__global__ void deg_kernel(const int* dst32, int* deg) {
  long stride = (long)gridDim.x * blockDim.x;
  for (long e = (long)blockIdx.x * blockDim.x + threadIdx.x; e < ETOT; e += stride) {
    int d = (e < NEDGES) ? dst32[e] : (int)(e - NEDGES);
    atomicAdd(&deg[d], 1);
  }
}

__global__ __launch_bounds__(1024) void scan_kernel(const int* deg, int* row_start, int* cursor) {
  __shared__ int part[1024];
  const int CH = (NNODES + 1023) / 1024;
  int t = threadIdx.x;
  int lo = t * CH;
  int hi = lo + CH; if (hi > NNODES) hi = NNODES; if (lo > NNODES) lo = NNODES;
  int s = 0;
  for (int i = lo; i < hi; i++) s += deg[i];
  part[t] = s;
  __syncthreads();
  for (int off = 1; off < 1024; off <<= 1) {
    int v = (t >= off) ? part[t - off] : 0;
    __syncthreads();
    part[t] += v;
    __syncthreads();
  }
  int run = (t == 0) ? 0 : part[t - 1];
  for (int i = lo; i < hi; i++) {
    row_start[i] = run;
    cursor[i] = run;
    run += deg[i];
  }
  if (t == 1023) row_start[NNODES] = part[1023];
}

__global__ void scatter_kernel(const int* src32, const int* dst32, int* cursor, int* adj) {
  long stride = (long)gridDim.x * blockDim.x;
  for (long e = (long)blockIdx.x * blockDim.x + threadIdx.x; e < ETOT; e += stride) {
    int d, s;
    if (e < NEDGES) { d = dst32[e]; s = src32[e]; }
    else { d = (int)(e - NEDGES); s = d; }
    int pos = atomicAdd(&cursor[d], 1);
    adj[pos] = s;
  }
}

// ---------------- per-layer kernels ----------------
// G = A @ W  (A: [N,128] fp32, W: 128x128 fp32 resident in LDS, 1 wave per row)
__global__ __launch_bounds__(256) void gemm128(const float* A, const float* wts, int w_off, float* G) {
  __shared__ float Ws[128 * 128];
  const float* W = wts + w_off;
  for (int i = threadIdx.x; i < 128 * 128; i += 256) Ws[i] = W[i];
  __syncthreads();
  int row = blockIdx.x * 4 + (threadIdx.x >> 6);
  int lane = threadIdx.x & 63;
  const float* Ar = A + (size_t)row * 128;
  float a0 = Ar[lane], a1 = Ar[64 + lane];
  float acc0 = 0.f, acc1 = 0.f;
#pragma unroll
  for (int k = 0; k < 64; k++) {
    float ak = __shfl(a0, k, 64);
    acc0 = fmaf(ak, Ws[k * 128 + lane], acc0);
    acc1 = fmaf(ak, Ws[k * 128 + 64 + lane], acc1);
  }
#pragma unroll
  for (int k = 0; k < 64; k++) {
    float ak = __shfl(a1, k, 64);
    acc0 = fmaf(ak, Ws[(64 + k) * 128 + lane], acc0);
    acc1 = fmaf(ak, Ws[(64 + k) * 128 + 64 + lane], acc1);
  }
  float* Gr = G + (size_t)row * 128;
  Gr[lane] = acc0;
  Gr[64 + lane] = acc1;
}

// al[n,h] = sum_c g[n,h,c]*as[h,c];  ar likewise. 1 wave per node.
__global__ __launch_bounds__(256) void attn_terms(const float* G, const float* wts, int as_off,
                                                  int ad_off, float* al, float* ar, int H) {
  int node = blockIdx.x * 4 + (threadIdx.x >> 6);
  int lane = threadIdx.x & 63;
  const float* asl = wts + as_off;
  const float* adl = wts + ad_off;
  float g0 = G[(size_t)node * 128 + lane];
  float g1 = G[(size_t)node * 128 + 64 + lane];
  if (H == 4) {
    float pa0 = g0 * asl[lane], pa1 = g1 * asl[64 + lane];
    float pb0 = g0 * adl[lane], pb1 = g1 * adl[64 + lane];
#pragma unroll
    for (int m = 1; m <= 16; m <<= 1) {
      pa0 += __shfl_xor(pa0, m, 64);
      pa1 += __shfl_xor(pa1, m, 64);
      pb0 += __shfl_xor(pb0, m, 64);
      pb1 += __shfl_xor(pb1, m, 64);
    }
    if ((lane & 31) == 0) {
      int hh = lane >> 5;  // 0 or 1
      al[(size_t)node * 4 + hh] = pa0;
      al[(size_t)node * 4 + 2 + hh] = pa1;
      ar[(size_t)node * 4 + hh] = pb0;
      ar[(size_t)node * 4 + 2 + hh] = pb1;
    }
  } else {
    float pa = g0 * asl[lane] + g1 * asl[64 + lane];
    float pb = g0 * adl[lane] + g1 * adl[64 + lane];
#pragma unroll
    for (int m = 1; m <= 32; m <<= 1) {
      pa += __shfl_xor(pa, m, 64);
      pb += __shfl_xor(pb, m, 64);
    }
    if (lane == 0) { al[node] = pa; ar[node] = pb; }
  }
}

// per-dst softmax + weighted gather. 1 block (128 threads) per dst node.
__global__ __launch_bounds__(128) void aggregate(const float* G, const float* al, const float* ar,
                                                 const float* wts, int b_off, const int* row_start,
                                                 const int* adj, float* out, int H, int relu) {
  int d = blockIdx.x;
  int t = threadIdx.x;
  int C = 128 / H;
  int h = t / C;
  float ar_d = ar[(size_t)d * H + h];
  int beg = row_start[d], end = row_start[d + 1];
  float m = -1e30f;
  for (int j = beg; j < end; j++) {
    int s = adj[j];
    float e = al[(size_t)s * H + h] + ar_d;
    e = (e > 0.f) ? e : 0.2f * e;
    m = fmaxf(m, e);
  }
  float sum = 0.f;
  for (int j = beg; j < end; j++) {
    int s = adj[j];
    float e = al[(size_t)s * H + h] + ar_d;
    e = (e > 0.f) ? e : 0.2f * e;
    sum += __expf(e - m);
  }
  float inv = 1.0f / (sum + 1e-16f);
  float acc = 0.f;
  for (int j = beg; j < end; j++) {
    int s = adj[j];
    float e = al[(size_t)s * H + h] + ar_d;
    e = (e > 0.f) ? e : 0.2f * e;
    float w = __expf(e - m) * inv;
    acc = fmaf(G[(size_t)s * 128 + t], w, acc);
  }
  float v = acc + wts[b_off + t];
  if (relu) v = fmaxf(v, 0.f);
  out[(size_t)d * 128 + t] = v;
}

__global__ void write_out_kernel(const float* src, void* dst, long n, const int* flags) {
  int f32 = flags[1];
  long stride = (long)gridDim.x * blockDim.x;
  for (long i = (long)blockIdx.x * blockDim.x + threadIdx.x; i < n; i += stride) {
    float v = src[i];
    if (f32) ((float*)dst)[i] = v;
    else ((__hip_bfloat16*)dst)[i] = __float2bfloat16(v);
  }
}

extern "C" void kernel_launch(void* const* d_in, const int* in_sizes, int n_in,
                              void* d_out, int out_size, void* d_ws, size_t ws_size,
                              hipStream_t stream) {
  char* ws = (char*)d_ws;
  size_t cur = 0;
  auto alloc = [&](size_t bytes) {
    size_t o = cur;
    cur += (bytes + 255) & ~(size_t)255;
    return o;
  };
  size_t off_flags = alloc(256);
  size_t off_wts = alloc(50304 * 4);
  size_t off_src = alloc((size_t)NEDGES * 4);
  size_t off_dst = alloc((size_t)NEDGES * 4);
  size_t off_deg = alloc((size_t)NNODES * 4);
  size_t off_rs = alloc(((size_t)NNODES + 1) * 4);
  size_t off_cur = alloc((size_t)NNODES * 4);
  size_t off_adj = alloc((size_t)ETOT * 4);
  size_t off_al = alloc((size_t)NNODES * 4 * 4);
  size_t off_ar = alloc((size_t)NNODES * 4 * 4);
  size_t off_x = alloc((size_t)NNODES * 128 * 4);
  size_t off_g = alloc((size_t)NNODES * 128 * 4);
  size_t off_ha = alloc((size_t)NNODES * 128 * 4);
  size_t off_hb = alloc((size_t)NNODES * 128 * 4);

  int* flags = (int*)(ws + off_flags);
  float* wts = (float*)(ws + off_wts);
  int* src32 = (int*)(ws + off_src);
  int* dst32 = (int*)(ws + off_dst);
  int* deg = (int*)(ws + off_deg);
  int* rs = (int*)(ws + off_rs);
  int* curs = (int*)(ws + off_cur);
  int* adj = (int*)(ws + off_adj);
  float* al = (float*)(ws + off_al);
  float* ar = (float*)(ws + off_ar);
  float* xf = (float*)(ws + off_x);
  float* G = (float*)(ws + off_g);
  float* ha = (float*)(ws + off_ha);
  float* hb = (float*)(ws + off_hb);

  detect_kernel<<<1, 256, 0, stream>>>(d_in[0], d_in[1], flags);

  WSrc wsrc;
  for (int i = 0; i < 12; i++) wsrc.p[i] = d_in[2 + i];
  conv_wts_kernel<<<64, 256, 0, stream>>>(wsrc, wts, flags);
  conv_f32_kernel<<<4096, 256, 0, stream>>>(d_in[0], xf, (long)NNODES * 128, flags);
  conv_edges_kernel<<<4096, 256, 0, stream>>>(d_in[1], src32, dst32, flags);

  hipMemsetAsync(deg, 0, (size_t)NNODES * 4, stream);
  deg_kernel<<<4096, 256, 0, stream>>>(dst32, deg);
  scan_kernel<<<1, 1024, 0, stream>>>(deg, rs, curs);
  scatter_kernel<<<4096, 256, 0, stream>>>(src32, dst32, curs, adj);

  // layer 0: x -> ha (relu)
  gemm128<<<NNODES / 4, 256, 0, stream>>>(xf, wts, 0, G);
  attn_terms<<<NNODES / 4, 256, 0, stream>>>(G, wts, 16384, 16512, al, ar, 4);
  aggregate<<<NNODES, 128, 0, stream>>>(G, al, ar, wts, 16640, rs, adj, ha, 4, 1);
  // layer 1: ha -> hb (relu)
  gemm128<<<NNODES / 4, 256, 0, stream>>>(ha, wts, 16768, G);
  attn_terms<<<NNODES / 4, 256, 0, stream>>>(G, wts, 33152, 33280, al, ar, 4);
  aggregate<<<NNODES, 128, 0, stream>>>(G, al, ar, wts, 33408, rs, adj, hb, 4, 1);
  // layer 2: hb -> ha (no relu, H=1)
  gemm128<<<NNODES / 4, 256, 0, stream>>>(hb, wts, 33536, G);
  attn_terms<<<NNODES / 4, 256, 0, stream>>>(G, wts, 49920, 50048, al, ar, 1);
  aggregate<<<NNODES, 128, 0, stream>>>(G, al, ar, wts, 50176, rs, adj, ha, 1, 0);

  write_out_kernel<<<4096, 256, 0, stream>>>(ha, d_out, (long)out_size, flags);
}

// Round 3
// 1344.035 us; speedup vs baseline: 1.9816x; 1.9816x over previous
//
#include <hip/hip_runtime.h>
#include <hip/hip_bf16.h>

#define NNODES 100000
#define NEDGES 1600000
#define ETOT   (NEDGES + NNODES)

struct WSrc { const void* p[12]; };

__device__ __forceinline__ float ld_f(const void* p, long i, int f32) {
  if (f32) return ((const float*)p)[i];
  return __bfloat162float(((const __hip_bfloat16*)p)[i]);
}

__device__ __forceinline__ unsigned short f2bf_bits(float v) {
  __hip_bfloat16 b = __float2bfloat16(v);
  return __builtin_bit_cast(unsigned short, b);
}

// ---------------- dtype detection ----------------
// flags[0]: 1 => edge_index is int64, else int32
// flags[1]: 1 => float buffers are fp32, else bf16
__global__ void detect_kernel(const void* xraw, const void* eraw, int* flags) {
  __shared__ int cnt0, cnt1;
  if (threadIdx.x == 0) { cnt0 = 0; cnt1 = 0; }
  __syncthreads();
  const int* e32 = (const int*)eraw;
  int nz = 0;
  for (int i = threadIdx.x; i < 2048; i += blockDim.x) nz += (e32[2 * i + 1] != 0);
  const unsigned short* xs = (const unsigned short*)xraw;
  int weird = 0;
  for (int i = threadIdx.x; i < 4096; i += blockDim.x) {
    unsigned short u = xs[2 * i];
    int ex = (u >> 7) & 0xFF;
    weird += (ex > 168 || (ex < 88 && ex != 0)) ? 1 : 0;
  }
  atomicAdd(&cnt0, nz);
  atomicAdd(&cnt1, weird);
  __syncthreads();
  if (threadIdx.x == 0) {
    flags[0] = (cnt0 < 1024) ? 1 : 0;
    flags[1] = (cnt1 > 512) ? 1 : 0;
  }
}

// ---------------- weights to fp32 ----------------
__global__ void conv_wts_kernel(WSrc wsrc, float* dst, const int* flags) {
  const int start[13] = {0, 16384, 16512, 16640, 16768, 33152, 33280, 33408,
                         33536, 49920, 50048, 50176, 50304};
  int f32 = flags[1];
  int stride = gridDim.x * blockDim.x;
  for (int i = blockIdx.x * blockDim.x + threadIdx.x; i < 50304; i += stride) {
    int s = 0;
    while (start[s + 1] <= i) s++;
    dst[i] = ld_f(wsrc.p[s], i - start[s], f32);
  }
}

__global__ void conv_edges_kernel(const void* raw, int* src32, int* dst32, const int* flags) {
  int i64 = flags[0];
  long stride = (long)gridDim.x * blockDim.x;
  for (long e = (long)blockIdx.x * blockDim.x + threadIdx.x; e < NEDGES; e += stride) {
    if (i64) {
      const long long* r = (const long long*)raw;
      src32[e] = (int)r[e];
      dst32[e] = (int)r[NEDGES + e];
    } else {
      const int* r = (const int*)raw;
      src32[e] = r[e];
      dst32[e] = r[NEDGES + e];
    }
  }
}

// ---------------- CSR build (by dst, self-loops appended) ----------------
__global__ void deg_kernel(const int* dst32, int* deg) {
  long stride = (long)gridDim.x * blockDim.x;
  for (long e = (long)blockIdx.x * blockDim.x + threadIdx.x; e < ETOT; e += stride) {
    int d = (e < NEDGES) ? dst32[e] : (int)(e - NEDGES);
    atomicAdd(&deg[d], 1);
  }
}

__global__ __launch_bounds__(1024) void scan_kernel(const int* deg, int* row_start, int* cursor) {
  __shared__ int part[1024];
  const int CH = (NNODES + 1023) / 1024;
  int t = threadIdx.x;
  int lo = t * CH;
  int hi = lo + CH; if (hi > NNODES) hi = NNODES; if (lo > NNODES) lo = NNODES;
  int s = 0;
  for (int i = lo; i < hi; i++) s += deg[i];
  part[t] = s;
  __syncthreads();
  for (int off = 1; off < 1024; off <<= 1) {
    int v = (t >= off) ? part[t - off] : 0;
    __syncthreads();
    part[t] += v;
    __syncthreads();
  }
  int run = (t == 0) ? 0 : part[t - 1];
  for (int i = lo; i < hi; i++) {
    row_start[i] = run;
    cursor[i] = run;
    run += deg[i];
  }
  if (t == 1023) row_start[NNODES] = part[1023];
}

__global__ void scatter_kernel(const int* src32, const int* dst32, int* cursor, int* adj) {
  long stride = (long)gridDim.x * blockDim.x;
  for (long e = (long)blockIdx.x * blockDim.x + threadIdx.x; e < ETOT; e += stride) {
    int d, s;
    if (e < NEDGES) { d = dst32[e]; s = src32[e]; }
    else { d = (int)(e - NEDGES); s = d; }
    int pos = atomicAdd(&cursor[d], 1);
    adj[pos] = s;
  }
}

// ---------------- fused GEMM + attention terms ----------------
// G = A @ W; al/ar computed from accumulators in-register.
// Block = 256 threads = 4 waves; 2 rows per wave => 8 rows per block.
// Lane l owns output channels (2l, 2l+1).
template <int H>
__global__ __launch_bounds__(256) void gemm_fused(const void* Araw, int araw, const float* wts,
                                                  int w_off, int as_off, int ad_off, float* G,
                                                  float* al, float* ar, const int* flags) {
  __shared__ float Ws[128 * 128];
  __shared__ float As[8 * 128];
  int f32 = flags[1];
  const float* W = wts + w_off;
  for (int i = threadIdx.x; i < 128 * 128; i += 256) Ws[i] = W[i];
  int rowbase = blockIdx.x * 8;
  for (int i = threadIdx.x; i < 8 * 128; i += 256) {
    long gi = (long)rowbase * 128 + i;
    As[i] = araw ? ld_f(Araw, gi, f32) : ((const float*)Araw)[gi];
  }
  __syncthreads();
  int wv = threadIdx.x >> 6, l = threadIdx.x & 63;
  int r0 = 2 * wv, r1 = 2 * wv + 1;
  float2 acc0 = {0.f, 0.f}, acc1 = {0.f, 0.f};
  const float* WL = Ws + 2 * l;
#pragma unroll 4
  for (int k0 = 0; k0 < 32; k0++) {
    float4 a0 = *(const float4*)&As[r0 * 128 + 4 * k0];
    float4 a1 = *(const float4*)&As[r1 * 128 + 4 * k0];
#pragma unroll
    for (int j = 0; j < 4; j++) {
      float2 w2 = *(const float2*)&WL[(4 * k0 + j) * 128];
      float av0 = (&a0.x)[j], av1 = (&a1.x)[j];
      acc0.x = fmaf(av0, w2.x, acc0.x);
      acc0.y = fmaf(av0, w2.y, acc0.y);
      acc1.x = fmaf(av1, w2.x, acc1.x);
      acc1.y = fmaf(av1, w2.y, acc1.y);
    }
  }
  int gr0 = rowbase + r0, gr1 = rowbase + r1;
  *(float2*)&G[(size_t)gr0 * 128 + 2 * l] = acc0;
  *(float2*)&G[(size_t)gr1 * 128 + 2 * l] = acc1;
  // attention terms
  float2 s2 = *(const float2*)&wts[as_off + 2 * l];
  float2 d2 = *(const float2*)&wts[ad_off + 2 * l];
  float pa0 = acc0.x * s2.x + acc0.y * s2.y;
  float pb0 = acc0.x * d2.x + acc0.y * d2.y;
  float pa1 = acc1.x * s2.x + acc1.y * s2.y;
  float pb1 = acc1.x * d2.x + acc1.y * d2.y;
  const int lim = (H == 4) ? 8 : 32;
#pragma unroll
  for (int msk = 1; msk <= lim; msk <<= 1) {
    pa0 += __shfl_xor(pa0, msk, 64);
    pb0 += __shfl_xor(pb0, msk, 64);
    pa1 += __shfl_xor(pa1, msk, 64);
    pb1 += __shfl_xor(pb1, msk, 64);
  }
  if (H == 4) {
    if ((l & 15) == 0) {
      int h = l >> 4;
      al[(size_t)gr0 * 4 + h] = pa0;
      ar[(size_t)gr0 * 4 + h] = pb0;
      al[(size_t)gr1 * 4 + h] = pa1;
      ar[(size_t)gr1 * 4 + h] = pb1;
    }
  } else {
    if (l == 0) {
      al[gr0] = pa0; ar[gr0] = pb0;
      al[gr1] = pa1; ar[gr1] = pb1;
    }
  }
}

// ---------------- flash-style aggregation: one wave per dst node ----------------
// Lane l: edge slot (l>>2), head (l&3) (H=4; replicated for H=1).
// Online softmax over 16-edge chunks; channels (2l,2l+1) accumulated per lane.
template <int H, int RELU, int OUTCONV>
__global__ __launch_bounds__(256) void aggregate2(const float* G, const float* al, const float* ar,
                                                  const float* wts, int b_off, const int* rs,
                                                  const int* adj, void* out, const int* flags) {
  int node = blockIdx.x * 4 + (threadIdx.x >> 6);
  if (node >= NNODES) return;
  int l = threadIdx.x & 63;
  int hh = (l & 3) & (H - 1);
  int hA = l >> 4;  // head of channels (2l,2l+1); for H=1 sub-lanes are replicas so this still works
  float ar_d = ar[(size_t)node * H + hh];
  int beg = rs[node], end = rs[node + 1];
  float m = -1e30f, sum = 0.f;
  float accx = 0.f, accy = 0.f;
  for (int base = beg; base < end; base += 16) {
    int slot = base + (l >> 2);
    int s = (slot < end) ? adj[slot] : -1;
    float e = -1e30f;
    if (s >= 0) {
      float v = al[(size_t)s * H + hh] + ar_d;
      e = (v > 0.f) ? v : 0.2f * v;
    }
    float cm = e;
    cm = fmaxf(cm, __shfl_xor(cm, 4, 64));
    cm = fmaxf(cm, __shfl_xor(cm, 8, 64));
    cm = fmaxf(cm, __shfl_xor(cm, 16, 64));
    cm = fmaxf(cm, __shfl_xor(cm, 32, 64));
    float mn = fmaxf(m, cm);
    float scale = __expf(m - mn);
    float p = __expf(e - mn);
    float cs = p;
    cs += __shfl_xor(cs, 4, 64);
    cs += __shfl_xor(cs, 8, 64);
    cs += __shfl_xor(cs, 16, 64);
    cs += __shfl_xor(cs, 32, 64);
    sum = sum * scale + cs;
    m = mn;
    float scA = __shfl(scale, hA, 64);
    accx *= scA;
    accy *= scA;
#pragma unroll
    for (int j = 0; j < 16; j++) {
      int sj = __shfl(s, 4 * j, 64);
      if (sj < 0) continue;  // wave-uniform
      float aA = __shfl(p, 4 * j + hA, 64);
      const float2 g2 = *(const float2*)&G[(size_t)sj * 128 + 2 * l];
      accx = fmaf(aA, g2.x, accx);
      accy = fmaf(aA, g2.y, accy);
    }
  }
  float inv = 1.f / (__shfl(sum, hA, 64) + 1e-16f);
  float2 b2 = *(const float2*)&wts[b_off + 2 * l];
  float ox = accx * inv + b2.x;
  float oy = accy * inv + b2.y;
  if (RELU) {
    ox = fmaxf(ox, 0.f);
    oy = fmaxf(oy, 0.f);
  }
  size_t oi = (size_t)node * 128 + 2 * l;
  if (OUTCONV) {
    if (flags[1]) {
      *(float2*)&((float*)out)[oi] = make_float2(ox, oy);
    } else {
      *(ushort2*)&((unsigned short*)out)[oi] = make_ushort2(f2bf_bits(ox), f2bf_bits(oy));
    }
  } else {
    *(float2*)&((float*)out)[oi] = make_float2(ox, oy);
  }
}

extern "C" void kernel_launch(void* const* d_in, const int* in_sizes, int n_in,
                              void* d_out, int out_size, void* d_ws, size_t ws_size,
                              hipStream_t stream) {
  char* ws = (char*)d_ws;
  size_t cur = 0;
  auto alloc = [&](size_t bytes) {
    size_t o = cur;
    cur += (bytes + 255) & ~(size_t)255;
    return o;
  };
  size_t off_flags = alloc(256);
  size_t off_wts = alloc(50304 * 4);
  size_t off_src = alloc((size_t)NEDGES * 4);
  size_t off_dst = alloc((size_t)NEDGES * 4);
  size_t off_deg = alloc((size_t)NNODES * 4);
  size_t off_rs = alloc(((size_t)NNODES + 1) * 4);
  size_t off_cur = alloc((size_t)NNODES * 4);
  size_t off_adj = alloc((size_t)ETOT * 4);
  size_t off_al = alloc((size_t)NNODES * 4 * 4);
  size_t off_ar = alloc((size_t)NNODES * 4 * 4);
  size_t off_g = alloc((size_t)NNODES * 128 * 4);
  size_t off_ha = alloc((size_t)NNODES * 128 * 4);
  size_t off_hb = alloc((size_t)NNODES * 128 * 4);

  int* flags = (int*)(ws + off_flags);
  float* wts = (float*)(ws + off_wts);
  int* src32 = (int*)(ws + off_src);
  int* dst32 = (int*)(ws + off_dst);
  int* deg = (int*)(ws + off_deg);
  int* rs = (int*)(ws + off_rs);
  int* curs = (int*)(ws + off_cur);
  int* adj = (int*)(ws + off_adj);
  float* al = (float*)(ws + off_al);
  float* ar = (float*)(ws + off_ar);
  float* G = (float*)(ws + off_g);
  float* ha = (float*)(ws + off_ha);
  float* hb = (float*)(ws + off_hb);

  detect_kernel<<<1, 256, 0, stream>>>(d_in[0], d_in[1], flags);

  WSrc wsrc;
  for (int i = 0; i < 12; i++) wsrc.p[i] = d_in[2 + i];
  conv_wts_kernel<<<64, 256, 0, stream>>>(wsrc, wts, flags);
  conv_edges_kernel<<<4096, 256, 0, stream>>>(d_in[1], src32, dst32, flags);

  (void)hipMemsetAsync(deg, 0, (size_t)NNODES * 4, stream);
  deg_kernel<<<4096, 256, 0, stream>>>(dst32, deg);
  scan_kernel<<<1, 1024, 0, stream>>>(deg, rs, curs);
  scatter_kernel<<<4096, 256, 0, stream>>>(src32, dst32, curs, adj);

  // layer 0: x -> ha (relu)
  gemm_fused<4><<<NNODES / 8, 256, 0, stream>>>(d_in[0], 1, wts, 0, 16384, 16512, G, al, ar, flags);
  aggregate2<4, 1, 0><<<NNODES / 4, 256, 0, stream>>>(G, al, ar, wts, 16640, rs, adj, ha, flags);
  // layer 1: ha -> hb (relu)
  gemm_fused<4><<<NNODES / 8, 256, 0, stream>>>(ha, 0, wts, 16768, 33152, 33280, G, al, ar, flags);
  aggregate2<4, 1, 0><<<NNODES / 4, 256, 0, stream>>>(G, al, ar, wts, 33408, rs, adj, hb, flags);
  // layer 2: hb -> out (no relu, H=1, fused output conversion)
  gemm_fused<1><<<NNODES / 8, 256, 0, stream>>>(hb, 0, wts, 33536, 49920, 50048, G, al, ar, flags);
  aggregate2<1, 0, 1><<<NNODES / 4, 256, 0, stream>>>(G, al, ar, wts, 50176, rs, adj, d_out, flags);
}

// Round 4
// 950.327 us; speedup vs baseline: 2.8025x; 1.4143x over previous
//
#include <hip/hip_runtime.h>
#include <hip/hip_bf16.h>
#include <hip/hip_fp16.h>

#define NNODES 100000
#define NEDGES 1600000
#define ETOT   (NEDGES + NNODES)
#define SCANB  1024
#define NSCAN  ((NNODES + SCANB - 1) / SCANB)  // 98

struct WSrc { const void* p[12]; };

__device__ __forceinline__ float ld_f(const void* p, long i, int f32) {
  if (f32) return ((const float*)p)[i];
  return __bfloat162float(((const __hip_bfloat16*)p)[i]);
}

__device__ __forceinline__ unsigned short f2bf_bits(float v) {
  __hip_bfloat16 b = __float2bfloat16(v);
  return __builtin_bit_cast(unsigned short, b);
}

// ---------------- dtype detection ----------------
// flags[0]: 1 => edge_index is int64, else int32
// flags[1]: 1 => float buffers are fp32, else bf16
__global__ void detect_kernel(const void* xraw, const void* eraw, int* flags) {
  __shared__ int cnt0, cnt1;
  if (threadIdx.x == 0) { cnt0 = 0; cnt1 = 0; }
  __syncthreads();
  const int* e32 = (const int*)eraw;
  int nz = 0;
  for (int i = threadIdx.x; i < 2048; i += blockDim.x) nz += (e32[2 * i + 1] != 0);
  const unsigned short* xs = (const unsigned short*)xraw;
  int weird = 0;
  for (int i = threadIdx.x; i < 4096; i += blockDim.x) {
    unsigned short u = xs[2 * i];
    int ex = (u >> 7) & 0xFF;
    weird += (ex > 168 || (ex < 88 && ex != 0)) ? 1 : 0;
  }
  atomicAdd(&cnt0, nz);
  atomicAdd(&cnt1, weird);
  __syncthreads();
  if (threadIdx.x == 0) {
    flags[0] = (cnt0 < 1024) ? 1 : 0;
    flags[1] = (cnt1 > 512) ? 1 : 0;
  }
}

// ---------------- weights to fp32 ----------------
__global__ void conv_wts_kernel(WSrc wsrc, float* dst, const int* flags) {
  const int start[13] = {0, 16384, 16512, 16640, 16768, 33152, 33280, 33408,
                         33536, 49920, 50048, 50176, 50304};
  int f32 = flags[1];
  int stride = gridDim.x * blockDim.x;
  for (int i = blockIdx.x * blockDim.x + threadIdx.x; i < 50304; i += stride) {
    int s = 0;
    while (start[s + 1] <= i) s++;
    dst[i] = ld_f(wsrc.p[s], i - start[s], f32);
  }
}

// edge conversion + fused dst-degree histogram (real edges only)
__global__ void conv_edges_kernel(const void* raw, int* src32, int* dst32, int* deg,
                                  const int* flags) {
  int i64 = flags[0];
  long stride = (long)gridDim.x * blockDim.x;
  for (long e = (long)blockIdx.x * blockDim.x + threadIdx.x; e < NEDGES; e += stride) {
    int s, d;
    if (i64) {
      const long long* r = (const long long*)raw;
      s = (int)r[e];
      d = (int)r[NEDGES + e];
    } else {
      const int* r = (const int*)raw;
      s = r[e];
      d = r[NEDGES + e];
    }
    src32[e] = s;
    dst32[e] = d;
    atomicAdd(&deg[d], 1);
  }
}

// ---------------- multi-block exclusive scan of (deg[i]+1) ----------------
__global__ __launch_bounds__(1024) void scan_part(const int* deg, int* part) {
  __shared__ int lds[SCANB];
  int b = blockIdx.x, t = threadIdx.x;
  int idx = b * SCANB + t;
  lds[t] = (idx < NNODES) ? deg[idx] + 1 : 0;
  __syncthreads();
  for (int off = 512; off > 0; off >>= 1) {
    if (t < off) lds[t] += lds[t + off];
    __syncthreads();
  }
  if (t == 0) part[b] = lds[0];
}

__global__ __launch_bounds__(128) void scan_tops(int* part) {
  __shared__ int lds[128];
  int t = threadIdx.x;
  lds[t] = (t < NSCAN) ? part[t] : 0;
  __syncthreads();
  for (int off = 1; off < 128; off <<= 1) {
    int v = (t >= off) ? lds[t - off] : 0;
    __syncthreads();
    lds[t] += v;
    __syncthreads();
  }
  if (t < NSCAN) part[t] = (t == 0) ? 0 : lds[t - 1];
}

__global__ __launch_bounds__(1024) void scan_write(const int* deg, const int* part, int* rs,
                                                   int* cursor) {
  __shared__ int lds[SCANB];
  int b = blockIdx.x, t = threadIdx.x;
  int idx = b * SCANB + t;
  int x = (idx < NNODES) ? deg[idx] + 1 : 0;
  lds[t] = x;
  __syncthreads();
  for (int off = 1; off < SCANB; off <<= 1) {
    int v = (t >= off) ? lds[t - off] : 0;
    __syncthreads();
    lds[t] += v;
    __syncthreads();
  }
  int incl = part[b] + lds[t];
  int excl = incl - x;
  if (idx < NNODES) {
    rs[idx] = excl;
    cursor[idx] = excl;
  }
  if (idx == NNODES - 1) rs[NNODES] = incl;
}

__global__ void scatter_kernel(const int* src32, const int* dst32, int* cursor, int* adj) {
  long stride = (long)gridDim.x * blockDim.x;
  for (long e = (long)blockIdx.x * blockDim.x + threadIdx.x; e < ETOT; e += stride) {
    int d, s;
    if (e < NEDGES) { d = dst32[e]; s = src32[e]; }
    else { d = (int)(e - NEDGES); s = d; }
    int pos = atomicAdd(&cursor[d], 1);
    adj[pos] = s;
  }
}

// ---------------- fused GEMM + attention terms ----------------
// G = A @ W (G stored fp16); al/ar from fp32 accumulators in-register.
// Block = 256 threads = 4 waves; 4 rows per wave => 16 rows per block.
// Lane l owns output channels (2l, 2l+1).
template <int H>
__global__ __launch_bounds__(256) void gemm_fused(const void* Araw, int araw, const float* wts,
                                                  int w_off, int as_off, int ad_off, __half* G,
                                                  float* al, float* ar, const int* flags) {
  __shared__ float Ws[128 * 128];
  __shared__ float As[16 * 128];
  int f32 = flags[1];
  const float* W = wts + w_off;
  for (int i = threadIdx.x; i < 128 * 128; i += 256) Ws[i] = W[i];
  int rowbase = blockIdx.x * 16;
  for (int i = threadIdx.x; i < 16 * 128; i += 256) {
    long gi = (long)rowbase * 128 + i;
    As[i] = araw ? ld_f(Araw, gi, f32) : ((const float*)Araw)[gi];
  }
  __syncthreads();
  int wv = threadIdx.x >> 6, l = threadIdx.x & 63;
  int rbase = wv * 4;
  float2 acc[4] = {{0.f, 0.f}, {0.f, 0.f}, {0.f, 0.f}, {0.f, 0.f}};
  const float* WL = Ws + 2 * l;
#pragma unroll 2
  for (int k0 = 0; k0 < 32; k0++) {
    float4 a[4];
#pragma unroll
    for (int r = 0; r < 4; r++) a[r] = *(const float4*)&As[(rbase + r) * 128 + 4 * k0];
#pragma unroll
    for (int j = 0; j < 4; j++) {
      float2 w2 = *(const float2*)&WL[(4 * k0 + j) * 128];
#pragma unroll
      for (int r = 0; r < 4; r++) {
        float av = (&a[r].x)[j];
        acc[r].x = fmaf(av, w2.x, acc[r].x);
        acc[r].y = fmaf(av, w2.y, acc[r].y);
      }
    }
  }
  float2 s2 = *(const float2*)&wts[as_off + 2 * l];
  float2 d2 = *(const float2*)&wts[ad_off + 2 * l];
#pragma unroll
  for (int r = 0; r < 4; r++) {
    int gr = rowbase + rbase + r;
    *(__half2*)&G[(size_t)gr * 128 + 2 * l] = __floats2half2_rn(acc[r].x, acc[r].y);
    float pa = acc[r].x * s2.x + acc[r].y * s2.y;
    float pb = acc[r].x * d2.x + acc[r].y * d2.y;
    const int lim = (H == 4) ? 8 : 32;
#pragma unroll
    for (int msk = 1; msk <= lim; msk <<= 1) {
      pa += __shfl_xor(pa, msk, 64);
      pb += __shfl_xor(pb, msk, 64);
    }
    if (H == 4) {
      if ((l & 15) == 0) {
        int h = l >> 4;
        al[(size_t)gr * 4 + h] = pa;
        ar[(size_t)gr * 4 + h] = pb;
      }
    } else {
      if (l == 0) { al[gr] = pa; ar[gr] = pb; }
    }
  }
}

// ---------------- flash-style aggregation: one wave per dst node ----------------
// Lane l: edge slot (l>>2), head (l&3) (H=4; replicated for H=1).
// Online softmax over 16-edge chunks; channels (2l,2l+1) accumulated per lane.
template <int H, int RELU, int OUTCONV>
__global__ __launch_bounds__(256) void aggregate2(const __half* G, const float* al, const float* ar,
                                                  const float* wts, int b_off, const int* rs,
                                                  const int* adj, void* out, const int* flags) {
  int node = blockIdx.x * 4 + (threadIdx.x >> 6);
  if (node >= NNODES) return;
  int l = threadIdx.x & 63;
  int hh = (l & 3) & (H - 1);
  int hA = l >> 4;  // head of channels (2l,2l+1); for H=1 sub-lanes are replicas
  float ar_d = ar[(size_t)node * H + hh];
  int beg = rs[node], end = rs[node + 1];
  float m = -1e30f, sum = 0.f;
  float accx = 0.f, accy = 0.f;
  for (int base = beg; base < end; base += 16) {
    int slot = base + (l >> 2);
    int s = (slot < end) ? adj[slot] : -1;
    float e = -1e30f;
    if (s >= 0) {
      float v = al[(size_t)s * H + hh] + ar_d;
      e = (v > 0.f) ? v : 0.2f * v;
    }
    float cm = e;
    cm = fmaxf(cm, __shfl_xor(cm, 4, 64));
    cm = fmaxf(cm, __shfl_xor(cm, 8, 64));
    cm = fmaxf(cm, __shfl_xor(cm, 16, 64));
    cm = fmaxf(cm, __shfl_xor(cm, 32, 64));
    float mn = fmaxf(m, cm);
    float scale = __expf(m - mn);
    float p = __expf(e - mn);
    float cs = p;
    cs += __shfl_xor(cs, 4, 64);
    cs += __shfl_xor(cs, 8, 64);
    cs += __shfl_xor(cs, 16, 64);
    cs += __shfl_xor(cs, 32, 64);
    sum = sum * scale + cs;
    m = mn;
    float scA = __shfl(scale, hA, 64);
    accx *= scA;
    accy *= scA;
#pragma unroll
    for (int j = 0; j < 16; j++) {
      int sj = __shfl(s, 4 * j, 64);
      if (sj < 0) continue;  // wave-uniform
      float aA = __shfl(p, 4 * j + hA, 64);
      __half2 g2h = *(const __half2*)&G[(size_t)sj * 128 + 2 * l];
      float2 g2 = __half22float2(g2h);
      accx = fmaf(aA, g2.x, accx);
      accy = fmaf(aA, g2.y, accy);
    }
  }
  float inv = 1.f / (__shfl(sum, hA, 64) + 1e-16f);
  float2 b2 = *(const float2*)&wts[b_off + 2 * l];
  float ox = accx * inv + b2.x;
  float oy = accy * inv + b2.y;
  if (RELU) {
    ox = fmaxf(ox, 0.f);
    oy = fmaxf(oy, 0.f);
  }
  size_t oi = (size_t)node * 128 + 2 * l;
  if (OUTCONV) {
    if (flags[1]) {
      *(float2*)&((float*)out)[oi] = make_float2(ox, oy);
    } else {
      *(ushort2*)&((unsigned short*)out)[oi] = make_ushort2(f2bf_bits(ox), f2bf_bits(oy));
    }
  } else {
    *(float2*)&((float*)out)[oi] = make_float2(ox, oy);
  }
}

extern "C" void kernel_launch(void* const* d_in, const int* in_sizes, int n_in,
                              void* d_out, int out_size, void* d_ws, size_t ws_size,
                              hipStream_t stream) {
  char* ws = (char*)d_ws;
  size_t cur = 0;
  auto alloc = [&](size_t bytes) {
    size_t o = cur;
    cur += (bytes + 255) & ~(size_t)255;
    return o;
  };
  size_t off_flags = alloc(256);
  size_t off_wts = alloc(50304 * 4);
  size_t off_src = alloc((size_t)NEDGES * 4);
  size_t off_dst = alloc((size_t)NEDGES * 4);
  size_t off_deg = alloc((size_t)NNODES * 4);
  size_t off_part = alloc((size_t)NSCAN * 4 + 256);
  size_t off_rs = alloc(((size_t)NNODES + 1) * 4);
  size_t off_cur = alloc((size_t)NNODES * 4);
  size_t off_adj = alloc((size_t)ETOT * 4);
  size_t off_al = alloc((size_t)NNODES * 4 * 4);
  size_t off_ar = alloc((size_t)NNODES * 4 * 4);
  size_t off_g = alloc((size_t)NNODES * 128 * 2);
  size_t off_ha = alloc((size_t)NNODES * 128 * 4);
  size_t off_hb = alloc((size_t)NNODES * 128 * 4);

  int* flags = (int*)(ws + off_flags);
  float* wts = (float*)(ws + off_wts);
  int* src32 = (int*)(ws + off_src);
  int* dst32 = (int*)(ws + off_dst);
  int* deg = (int*)(ws + off_deg);
  int* part = (int*)(ws + off_part);
  int* rs = (int*)(ws + off_rs);
  int* curs = (int*)(ws + off_cur);
  int* adj = (int*)(ws + off_adj);
  float* al = (float*)(ws + off_al);
  float* ar = (float*)(ws + off_ar);
  __half* G = (__half*)(ws + off_g);
  float* ha = (float*)(ws + off_ha);
  float* hb = (float*)(ws + off_hb);

  detect_kernel<<<1, 256, 0, stream>>>(d_in[0], d_in[1], flags);

  WSrc wsrc;
  for (int i = 0; i < 12; i++) wsrc.p[i] = d_in[2 + i];
  conv_wts_kernel<<<64, 256, 0, stream>>>(wsrc, wts, flags);

  (void)hipMemsetAsync(deg, 0, (size_t)NNODES * 4, stream);
  conv_edges_kernel<<<4096, 256, 0, stream>>>(d_in[1], src32, dst32, deg, flags);
  scan_part<<<NSCAN, 1024, 0, stream>>>(deg, part);
  scan_tops<<<1, 128, 0, stream>>>(part);
  scan_write<<<NSCAN, 1024, 0, stream>>>(deg, part, rs, curs);
  scatter_kernel<<<4096, 256, 0, stream>>>(src32, dst32, curs, adj);

  // layer 0: x -> ha (relu)
  gemm_fused<4><<<NNODES / 16, 256, 0, stream>>>(d_in[0], 1, wts, 0, 16384, 16512, G, al, ar, flags);
  aggregate2<4, 1, 0><<<NNODES / 4, 256, 0, stream>>>(G, al, ar, wts, 16640, rs, adj, ha, flags);
  // layer 1: ha -> hb (relu)
  gemm_fused<4><<<NNODES / 16, 256, 0, stream>>>(ha, 0, wts, 16768, 33152, 33280, G, al, ar, flags);
  aggregate2<4, 1, 0><<<NNODES / 4, 256, 0, stream>>>(G, al, ar, wts, 33408, rs, adj, hb, flags);
  // layer 2: hb -> out (no relu, H=1, fused output conversion)
  gemm_fused<1><<<NNODES / 16, 256, 0, stream>>>(hb, 0, wts, 33536, 49920, 50048, G, al, ar, flags);
  aggregate2<1, 0, 1><<<NNODES / 4, 256, 0, stream>>>(G, al, ar, wts, 50176, rs, adj, d_out, flags);
}